// Round 13
// baseline (161.957 us; speedup 1.0000x reference)
//
#include <hip/hip_runtime.h>
#include <math.h>

// Problem constants (from reference setup): B=4, N=65536, M=128.
#define NPTS  65536
#define MBOX  128
#define TPB   1024
#define WAVES 16
#define PPB   512             // points per block (shared by all 16 waves)
#define PPL   8               // points per lane
#define SLICE (MBOX / WAVES)  // 8 boxes per wave
#define CHUNK 2               // boxes per load-batch (4 ds_read_b128 in flight)
#define SENT  999

// R12's box-sliced structure at doubled occupancy: 16 waves/block x 8-box
// slices, 2 blocks/CU -> 32 waves/CU = 8 waves/SIMD (vs R12's 4), with
// per-CU LDS box-read instruction count unchanged (512). VGPR forced <=64
// via __launch_bounds__(1024,8); CHUNK=2 keeps register pressure down
// (~58 VGPR est). Slice partials min-combined 16-way (slices are disjoint
// ascending index ranges, so min over partials == global first hit).
// Packed f32 math (VOP3P), contraction off: per-element rounding is
// mul,mul,add in rn — bit-identical to the reference (absmax=0 R1-R12).
__global__ __launch_bounds__(1024, 8) void pib_sliced(const float* __restrict__ points,
                                                      const float* __restrict__ boxes,
                                                      float* __restrict__ out) {
    #pragma clang fp contract(off)
    __shared__ float srec[MBOX * 8];     //  4 KB derived records
    __shared__ int   part[WAVES * PPB];  // 32 KB slice partials

    const int blocksPerBatch = NPTS / PPB;   // 128
    int b    = blockIdx.x >> 7;
    int blk  = blockIdx.x & 127;
    int wv   = threadIdx.x >> 6;
    int lane = threadIdx.x & 63;

    // Lane's 8 points, issued before the barrier so global latency hides
    // under the box-derive. All 16 waves load the same 512 points (L1 hits
    // after the first wave). 24 floats = 6x float4 (pbase*3*4B % 96 == 0).
    size_t pbase = (size_t)b * NPTS + (size_t)blk * PPB + (size_t)lane * PPL;
    const float* pp = points + pbase * 3;
    float4 v0 = *(const float4*)(pp);
    float4 v1 = *(const float4*)(pp + 4);
    float4 v2 = *(const float4*)(pp + 8);
    float4 v3 = *(const float4*)(pp + 12);
    float4 v4 = *(const float4*)(pp + 16);
    float4 v5 = *(const float4*)(pp + 20);

    // Derive box records straight from global: thread t<128 reads box t's
    // 7 floats, computes cos/sin (accurate libm, matches numpy: absmax=0
    // R1-R12).
    if (threadIdx.x < MBOX) {
        const float* r = boxes + ((size_t)b * MBOX + threadIdx.x) * 7;
        float rz = r[6];
        float* o = srec + threadIdx.x * 8;
        o[0] = r[0]; o[1] = r[1]; o[2] = r[2];
        o[3] = 0.5f * r[3];   // exact, matches ref dims*0.5
        o[4] = 0.5f * r[4];
        o[5] = 0.5f * r[5];
        o[6] = cosf(rz);
        o[7] = sinf(rz);
    }

    // 4 point-pairs in packed registers, built directly from the float4s
    // (all indices compile-time, rule #20).
    float2 PX[4], PY[4], PZ[4];
    PX[0] = make_float2(v0.x, v0.w); PY[0] = make_float2(v0.y, v1.x); PZ[0] = make_float2(v0.z, v1.y);
    PX[1] = make_float2(v1.z, v2.y); PY[1] = make_float2(v1.w, v2.z); PZ[1] = make_float2(v2.x, v2.w);
    PX[2] = make_float2(v3.x, v3.w); PY[2] = make_float2(v3.y, v4.x); PZ[2] = make_float2(v3.z, v4.y);
    PX[3] = make_float2(v4.z, v5.y); PY[3] = make_float2(v4.w, v5.z); PZ[3] = make_float2(v5.x, v5.w);

    __syncthreads();

    int IDX[PPL];
    #pragma unroll
    for (int k = 0; k < PPL; ++k) IDX[k] = SENT;

    const int mlo = wv * SLICE;
    #pragma unroll
    for (int base = mlo + SLICE - CHUNK; base >= mlo; base -= CHUNK) {
        float4 q[2 * CHUNK];              // 2 box records, loads batched
        #pragma unroll
        for (int k = 0; k < CHUNK; ++k) {
            q[2*k]   = ((const float4*)srec)[(base + k) * 2];     // uniform
            q[2*k+1] = ((const float4*)srec)[(base + k) * 2 + 1]; // -> bcast
        }
        #pragma unroll
        for (int k = CHUNK - 1; k >= 0; --k) {   // descending within slice
            const float4 Q0 = q[2*k], Q1 = q[2*k+1];
            const int M = base + k;
            #pragma unroll
            for (int j = 0; j < 4; ++j) {
                float2 lx = PX[j] - make_float2(Q0.x, Q0.x);
                float2 ly = PY[j] - make_float2(Q0.y, Q0.y);
                float2 lz = PZ[j] - make_float2(Q0.z, Q0.z);
                float2 t0 = lx * make_float2(Q1.z, Q1.z);   // lx*cr
                float2 t1 = ly * make_float2(Q1.w, Q1.w);   // ly*sr
                float2 t2 = ly * make_float2(Q1.z, Q1.z);   // ly*cr
                float2 t3 = lx * make_float2(Q1.w, Q1.w);   // lx*sr
                float2 X = t0 + t1;
                float2 Y = t2 - t3;   // rn(ly*cr - lx*sr) == rn(-lx*sr + ly*cr)
                bool in0 = (fabsf(X.x) <= Q0.w) & (fabsf(Y.x) <= Q1.x) &
                           (fabsf(lz.x) <= Q1.y);
                bool in1 = (fabsf(X.y) <= Q0.w) & (fabsf(Y.y) <= Q1.x) &
                           (fabsf(lz.y) <= Q1.y);
                IDX[2*j]     = in0 ? M : IDX[2*j];
                IDX[2*j + 1] = in1 ? M : IDX[2*j + 1];
            }
        }
    }

    // Publish slice partials (one-time; 4-way write aliasing negligible).
    *(int4*)&part[wv * PPB + lane * PPL]     = make_int4(IDX[0], IDX[1], IDX[2], IDX[3]);
    *(int4*)&part[wv * PPB + lane * PPL + 4] = make_int4(IDX[4], IDX[5], IDX[6], IDX[7]);
    __syncthreads();

    // Combine: thread t<512 owns point t; min over the 16 slice partials
    // (lanes read consecutive ints -> conflict-free; ~16 wave-instrs/wave).
    int t = threadIdx.x;
    if (t < PPB) {
        int m0 = SENT;
        #pragma unroll
        for (int w = 0; w < WAVES; ++w) m0 = min(m0, part[w * PPB + t]);
        out[(size_t)b * NPTS + (size_t)blk * PPB + t] = m0 < SENT ? (float)m0 : -1.0f;
    }
}

extern "C" void kernel_launch(void* const* d_in, const int* in_sizes, int n_in,
                              void* d_out, int out_size, void* d_ws, size_t ws_size,
                              hipStream_t stream) {
    const float* points = (const float*)d_in[0];   // [B, N, 3] f32
    const float* boxes  = (const float*)d_in[1];   // [B, M, 7] f32
    float* out = (float*)d_out;                    // [B, N]    f32

    int n_points = in_sizes[0] / 3;                // B*N = 262144
    int main_blocks = n_points / PPB;              // 512 = 2 blocks/CU

    pib_sliced<<<main_blocks, TPB, 0, stream>>>(points, boxes, out);
}

// Round 14
// 14.963 us; speedup vs baseline: 10.8237x; 10.8237x over previous
//
#include <hip/hip_runtime.h>
#include <math.h>

// Problem constants (from reference setup): B=4, N=65536, M=128.
#define NPTS  65536
#define MBOX  128
#define TPB   512
#define WAVES 8
#define PPB   512             // points per block (shared by all 8 waves)
#define PPL   8               // points per lane
#define SLICE (MBOX / WAVES)  // 16 boxes per wave
#define CHUNK 8               // boxes per load-batch (16 ds_read_b128 in flight)
#define SENT  999

// R12's proven structure (15.2 us), one variable changed: CHUNK 4 -> 8.
// Halves the per-slice lgkmcnt stall points (2 chunk boundaries instead of
// 4) and doubles ds_reads in flight. q[16] = 64 VGPR + ~40 live others
// ~= 105 < 128 budget of __launch_bounds__(512,4): no spill (R13's lesson:
// an under-budget VGPR cap silently spills to scratch — 184 MB/dispatch,
// 10x regression; never force occupancy past the register working set).
// 8 waves/block x 16-box slices, 2 blocks/CU -> 4 waves/SIMD; per-CU LDS
// box-read count unchanged. Partial first-hit per slice (descending
// overwrite), LDS 8-way min-combine (slices are disjoint ascending index
// ranges -> min over partials == global first hit). Packed f32 (VOP3P),
// contraction off: per-element rounding mul,mul,add in rn — bit-identical
// to the reference (absmax=0 R1-R12).
__global__ __launch_bounds__(512, 4) void pib_sliced(const float* __restrict__ points,
                                                     const float* __restrict__ boxes,
                                                     float* __restrict__ out) {
    #pragma clang fp contract(off)
    __shared__ float srec[MBOX * 8];     //  4 KB derived records
    __shared__ int   part[WAVES * PPB];  // 16 KB slice partials

    const int blocksPerBatch = NPTS / PPB;   // 128
    int b    = blockIdx.x >> 7;
    int blk  = blockIdx.x & 127;
    int wv   = threadIdx.x >> 6;
    int lane = threadIdx.x & 63;

    // Lane's 8 points, issued before the barrier so global latency hides
    // under the box-derive. All 8 waves load the same 512 points (L1 hits
    // after the first wave). 24 floats = 6x float4 (pbase*3*4B % 96 == 0).
    size_t pbase = (size_t)b * NPTS + (size_t)blk * PPB + (size_t)lane * PPL;
    const float* pp = points + pbase * 3;
    float4 v0 = *(const float4*)(pp);
    float4 v1 = *(const float4*)(pp + 4);
    float4 v2 = *(const float4*)(pp + 8);
    float4 v3 = *(const float4*)(pp + 12);
    float4 v4 = *(const float4*)(pp + 16);
    float4 v5 = *(const float4*)(pp + 20);

    // Derive box records straight from global: thread t<128 reads box t's
    // 7 floats, computes cos/sin (accurate libm, matches numpy: absmax=0
    // R1-R12).
    if (threadIdx.x < MBOX) {
        const float* r = boxes + ((size_t)b * MBOX + threadIdx.x) * 7;
        float rz = r[6];
        float* o = srec + threadIdx.x * 8;
        o[0] = r[0]; o[1] = r[1]; o[2] = r[2];
        o[3] = 0.5f * r[3];   // exact, matches ref dims*0.5
        o[4] = 0.5f * r[4];
        o[5] = 0.5f * r[5];
        o[6] = cosf(rz);
        o[7] = sinf(rz);
    }

    // 4 point-pairs in packed registers, built directly from the float4s
    // (all indices compile-time, rule #20).
    float2 PX[4], PY[4], PZ[4];
    PX[0] = make_float2(v0.x, v0.w); PY[0] = make_float2(v0.y, v1.x); PZ[0] = make_float2(v0.z, v1.y);
    PX[1] = make_float2(v1.z, v2.y); PY[1] = make_float2(v1.w, v2.z); PZ[1] = make_float2(v2.x, v2.w);
    PX[2] = make_float2(v3.x, v3.w); PY[2] = make_float2(v3.y, v4.x); PZ[2] = make_float2(v3.z, v4.y);
    PX[3] = make_float2(v4.z, v5.y); PY[3] = make_float2(v4.w, v5.z); PZ[3] = make_float2(v5.x, v5.w);

    __syncthreads();

    int IDX[PPL];
    #pragma unroll
    for (int k = 0; k < PPL; ++k) IDX[k] = SENT;

    const int mlo = wv * SLICE;
    #pragma unroll
    for (int base = mlo + SLICE - CHUNK; base >= mlo; base -= CHUNK) {
        float4 q[2 * CHUNK];              // 8 box records, loads batched
        #pragma unroll
        for (int k = 0; k < CHUNK; ++k) {
            q[2*k]   = ((const float4*)srec)[(base + k) * 2];     // uniform
            q[2*k+1] = ((const float4*)srec)[(base + k) * 2 + 1]; // -> bcast
        }
        #pragma unroll
        for (int k = CHUNK - 1; k >= 0; --k) {   // descending within slice
            const float4 Q0 = q[2*k], Q1 = q[2*k+1];
            const int M = base + k;
            #pragma unroll
            for (int j = 0; j < 4; ++j) {
                float2 lx = PX[j] - make_float2(Q0.x, Q0.x);
                float2 ly = PY[j] - make_float2(Q0.y, Q0.y);
                float2 lz = PZ[j] - make_float2(Q0.z, Q0.z);
                float2 t0 = lx * make_float2(Q1.z, Q1.z);   // lx*cr
                float2 t1 = ly * make_float2(Q1.w, Q1.w);   // ly*sr
                float2 t2 = ly * make_float2(Q1.z, Q1.z);   // ly*cr
                float2 t3 = lx * make_float2(Q1.w, Q1.w);   // lx*sr
                float2 X = t0 + t1;
                float2 Y = t2 - t3;   // rn(ly*cr - lx*sr) == rn(-lx*sr + ly*cr)
                bool in0 = (fabsf(X.x) <= Q0.w) & (fabsf(Y.x) <= Q1.x) &
                           (fabsf(lz.x) <= Q1.y);
                bool in1 = (fabsf(X.y) <= Q0.w) & (fabsf(Y.y) <= Q1.x) &
                           (fabsf(lz.y) <= Q1.y);
                IDX[2*j]     = in0 ? M : IDX[2*j];
                IDX[2*j + 1] = in1 ? M : IDX[2*j + 1];
            }
        }
    }

    // Publish slice partials (one-time; write conflicts negligible).
    *(int4*)&part[wv * PPB + lane * PPL]     = make_int4(IDX[0], IDX[1], IDX[2], IDX[3]);
    *(int4*)&part[wv * PPB + lane * PPL + 4] = make_int4(IDX[4], IDX[5], IDX[6], IDX[7]);
    __syncthreads();

    // Combine: thread t owns point t; min over the 8 slice partials
    // (lanes read consecutive ints -> 2 lanes/bank = free).
    int t = threadIdx.x;
    int m0 = SENT;
    #pragma unroll
    for (int w = 0; w < WAVES; ++w) m0 = min(m0, part[w * PPB + t]);
    out[(size_t)b * NPTS + (size_t)blk * PPB + t] = m0 < SENT ? (float)m0 : -1.0f;
}

extern "C" void kernel_launch(void* const* d_in, const int* in_sizes, int n_in,
                              void* d_out, int out_size, void* d_ws, size_t ws_size,
                              hipStream_t stream) {
    const float* points = (const float*)d_in[0];   // [B, N, 3] f32
    const float* boxes  = (const float*)d_in[1];   // [B, M, 7] f32
    float* out = (float*)d_out;                    // [B, N]    f32

    int n_points = in_sizes[0] / 3;                // B*N = 262144
    int main_blocks = n_points / PPB;              // 512 = 2 blocks/CU

    pib_sliced<<<main_blocks, TPB, 0, stream>>>(points, boxes, out);
}